// Round 13
// baseline (21301.141 us; speedup 1.0000x reference)
//
#include <hip/hip_runtime.h>
#include <math.h>

// Problem constants (from reference)
#define T_STEPS 8192
#define INPUT   64
#define UNITS   1024
#define NMOD    4
#define LEAKY   0.9f

// Decomposition: 16 WGs per module; module = blockIdx%8 residues 0..3
// (4..7 exit). WG = 1024 threads = 16 waves.
//
// Transposed ownership (R7, 13.3ms): lane l of EVERY wave owns column
// c = wgi*64+l for the POLL; wave w handles h-rows [64w,64w+64): it polls
// exactly WG w's 64 packed {tag|h} entries, deposits them in a wave-private
// LDS slice, re-reads as 16 uniform-address float4 broadcasts, FMAs against
// 64 per-lane weights.
//
// NEW (R13): DISTRIBUTED combine+publish. After the barrier, wave w combines
// columns [4w,4w+4): lane (s=l>>2, j=l&3) gathers part[pb][s][4w+j] (stride
// 65 padding spreads banks), 4x shfl_xor reduces over s, lanes 0-3 blend
// with their hprev and publish 4 columns each. Replaces the wave-0-only
// combine (16 serial strided reads + 64 stores from ONE wave while 15 idle).
//
// Hard-won rules:
//  - per-step __syncthreads is LOAD-BEARING (R5/R9: removal -> 2-7x collapse)
//  - dual publish (plain->L2 + agent->MALL) with 1:1 alternating poll is the
//    validated sync (R7 13.3 vs agent-only R12 16.1 vs fast-heavy R10 29.6):
//    sc0 hits for same-XCD pairs, agent covers the rest; more sc0 chokes L2.
#define K_WG        16
#define COLS_PER_WG 64
#define GRID        128
#define WGSIZE      1024

#define ENTRIES     (NMOD * UNITS)   // 4096 packed entries per buffer
// d_ws layout: slow[2][ENTRIES] then fast[2][ENTRIES], 64-bit {tag|value}.
#define WS_ULL      (4 * ENTRIES)

__global__ void init_ws_kernel(unsigned long long* __restrict__ b) {
    int i = blockIdx.x * blockDim.x + threadIdx.x;
    if (i < WS_ULL) b[i] = 0ULL;     // tag 0 < any t in 1..T
}

// tanh via exp2 + rcp: ~1e-6 rel err, correct saturation (verified R4).
__device__ __forceinline__ float tanh_fast(float x) {
    float e2x = __builtin_amdgcn_exp2f(x * 2.8853900817779268f); // 2*log2(e)
    float r   = __builtin_amdgcn_rcpf(e2x + 1.0f);
    return fmaf(-2.0f, r, 1.0f);
}

// L1-bypass (sc0) 8-byte load: served coherently from the LOCAL XCD's L2.
__device__ __forceinline__ unsigned long long load_l2(
        const unsigned long long* p) {
    unsigned long long v;
    asm volatile("global_load_dwordx2 %0, %1, off sc0\n\t"
                 "s_waitcnt vmcnt(0)"
                 : "=v"(v) : "v"(p) : "memory");
    return v;
}

__global__ __launch_bounds__(WGSIZE, 1)
void reservoir_persist(const float* __restrict__ u,
                       const float* __restrict__ kern,
                       const float* __restrict__ rec,
                       const float* __restrict__ bias,
                       float* __restrict__ out,
                       unsigned long long* __restrict__ slow,
                       unsigned long long* __restrict__ fast)
{
    const int wg  = blockIdx.x;
    const int res = wg & 7;
    if (res >= NMOD) return;             // residues 4..7 idle
    const int m   = res;                 // module 0..3
    const int wgi = wg >> 3;             // 0..15 within module

    const int tid  = threadIdx.x;
    const int w    = tid >> 6;           // wave 0..15  (row-slice owner)
    const int lane = tid & 63;
    const int s    = lane >> 2;          // summand index 0..15 (combine)
    const int j    = lane & 3;           // column-within-quad (combine)

    const int c       = wgi * COLS_PER_WG + lane;      // poll column
    const int cpub    = wgi * COLS_PER_WG + 4 * w + j; // publish column
    const int rowBase = 64 * w;                        // my wave's h-row slice

    __shared__ __align__(16) float h_slice[16][64]; // wave-private row slices
    __shared__ float part[2][16][65];               // dbuf partials, pad 65

    // ---- one-time preload of weights into registers ----
    const float* recm = rec + (size_t)m * UNITS * UNITS;
    float r[64];
#pragma unroll
    for (int jj = 0; jj < 16; ++jj)
#pragma unroll
        for (int e = 0; e < 4; ++e)
            r[4 * jj + e] = recm[(size_t)(rowBase + 4 * jj + e) * UNITS + c];
#pragma unroll
    for (int jj = 0; jj < 64; ++jj) asm volatile("" : "+v"(r[jj]));

    // input kernel slice: wave w folds u-rows [4w, 4w+4)
    const float* km = kern + (size_t)m * INPUT * UNITS;
    const float k0 = km[(size_t)(4 * w + 0) * UNITS + c];
    const float k1 = km[(size_t)(4 * w + 1) * UNITS + c];
    const float k2 = km[(size_t)(4 * w + 2) * UNITS + c];
    const float k3 = km[(size_t)(4 * w + 3) * UNITS + c];
    const float bc = bias[m * UNITS + cpub];   // bias for my PUBLISH column

    const float leak = LEAKY, omleak = 1.0f - LEAKY;

    h_slice[w][lane] = 0.0f;             // h_0 = 0 (wave-private slice)
    float hprev = 0.0f;                  // lanes 0-3: my publish column state
    __syncthreads();

    const size_t modOff = (size_t)m * UNITS;

    // u quad for step 1 (uses u[0]); uniform per wave
    float4 uq = *reinterpret_cast<const float4*>(u + 4 * w);

    for (int t = 1; t <= T_STEPS; ++t) {
        const int pb = t & 1;

        // ---- FMA phase: rows [64w,64w+64) x my column, h via LDS broadcast
        const float4* __restrict__ hs4 =
            reinterpret_cast<const float4*>(h_slice[w]);
        float a0 = uq.x * k0, a1 = uq.y * k1, a2 = uq.z * k2, a3 = uq.w * k3;
#pragma unroll
        for (int jj = 0; jj < 16; ++jj) {
            float4 hv4 = hs4[jj];        // uniform address -> HW broadcast
            a0 = fmaf(r[4 * jj + 0], hv4.x, a0);
            a1 = fmaf(r[4 * jj + 1], hv4.y, a1);
            a2 = fmaf(r[4 * jj + 2], hv4.z, a2);
            a3 = fmaf(r[4 * jj + 3], hv4.w, a3);
        }
        part[pb][w][lane] = (a0 + a1) + (a2 + a3);
        __syncthreads();   // partials of step t visible; only barrier/step

        unsigned long long* fbW = fast + (size_t)pb * ENTRIES + modOff;
        unsigned long long* sbW = slow + (size_t)pb * ENTRIES + modOff;

        // ---- DISTRIBUTED combine: wave w -> columns [4w, 4w+4) ----
        // lane (s,j) gathers part[pb][s][4w+j]; banks spread by 65-stride.
        // part[pb] reuse at t+2 is race-free: wave w's t+2 part-write needs
        // its (t+1)-poll <- WG w's (t+1)-publishes <- WG w's t+1 barrier <-
        // wave y of WG w's t-poll <- WG y's t-publishes <- their t-gathers.
        float ps = part[pb][s][4 * w + j];
        ps += __shfl_xor(ps, 4, 64);     // s ^= 1
        ps += __shfl_xor(ps, 8, 64);     // s ^= 2
        ps += __shfl_xor(ps, 16, 64);    // s ^= 4
        ps += __shfl_xor(ps, 32, 64);    // s ^= 8
        // every lane now holds the full dot for column 4w+j; lanes 0-3 own it
        float hn = omleak * hprev + leak * tanh_fast(ps + bc);
        if (lane < 4) {
            hprev = hn;
            unsigned long long pk =
                ((unsigned long long)(unsigned int)t << 32) |
                (unsigned long long)__float_as_uint(hn);
            // fast: plain store -> local XCD L2 (sc0-visible there)
            __hip_atomic_store(&fbW[cpub], pk, __ATOMIC_RELAXED,
                               __HIP_MEMORY_SCOPE_WORKGROUP);
            // slow: agent store -> MALL (any placement)
            __hip_atomic_store(&sbW[cpub], pk, __ATOMIC_RELAXED,
                               __HIP_MEMORY_SCOPE_AGENT);
        }

        // prefetch next u quad (latency overlaps the poll)
        if (t < T_STEPS)
            uq = *reinterpret_cast<const float4*>(u + (size_t)t * INPUT + 4 * w);

        // ---- poll my row slice (entry tid = 64w+lane): 1:1 fast/slow ----
        unsigned long long v;
        for (;;) {
            v = load_l2(&fbW[tid]);
            if ((unsigned int)(v >> 32) == (unsigned int)t) break;
            v = __hip_atomic_load(&sbW[tid], __ATOMIC_RELAXED,
                                  __HIP_MEMORY_SCOPE_AGENT);
            if ((unsigned int)(v >> 32) == (unsigned int)t) break;
        }
        const float hv = __uint_as_float((unsigned int)v);
        h_slice[w][lane] = hv;           // wave-private; in-wave ds ordering

        // one WG per module writes the coalesced output row (off crit path)
        if (wgi == 0)
            out[(size_t)(t - 1) * (NMOD * UNITS) + modOff + tid] = hv;
    }
}

extern "C" void kernel_launch(void* const* d_in, const int* in_sizes, int n_in,
                              void* d_out, int out_size, void* d_ws, size_t ws_size,
                              hipStream_t stream) {
    const float* u    = (const float*)d_in[0];  // [1, 8192, 64]
    const float* kern = (const float*)d_in[1];  // [4, 64, 1024]
    const float* rec  = (const float*)d_in[2];  // [4, 1024, 1024]
    const float* bias = (const float*)d_in[3];  // [4, 1024]
    float* out = (float*)d_out;                 // [1, 8192, 4096] f32

    unsigned long long* slow = (unsigned long long*)d_ws;              // 64 KB
    unsigned long long* fast = slow + 2 * ENTRIES;                     // 64 KB

    hipLaunchKernelGGL(init_ws_kernel, dim3((WS_ULL + 1023) / 1024), dim3(1024),
                       0, stream, slow);

    void* args[] = { (void*)&u, (void*)&kern, (void*)&rec, (void*)&bias,
                     (void*)&out, (void*)&slow, (void*)&fast };
    hipLaunchCooperativeKernel((const void*)reservoir_persist,
                               dim3(GRID), dim3(WGSIZE), args, 0, stream);
}

// Round 14
// 19002.690 us; speedup vs baseline: 1.1210x; 1.1210x over previous
//
#include <hip/hip_runtime.h>
#include <math.h>

// Problem constants (from reference)
#define T_STEPS 8192
#define INPUT   64
#define UNITS   1024
#define NMOD    4
#define LEAKY   0.9f

// Decomposition (R7 structure, best-known 13.3ms): 16 WGs per module;
// module = blockIdx%8 residues 0..3 (4..7 exit). WG = 1024 threads = 16
// waves. Lane l of EVERY wave owns column c = wgi*64+l for the POLL; wave w
// handles h-rows [64w,64w+64): polls exactly WG w's 64 packed {tag|h}
// entries, deposits them in a wave-private LDS slice, re-reads as 16
// uniform-address float4 broadcasts, FMAs against 64 per-lane weights.
// Partials combine in LDS after ONE barrier; wave 0 finishes + publishes.
//
// Hard-won rules:
//  - per-step __syncthreads is LOAD-BEARING (R5/R9: removal -> 2-7x collapse)
//  - dual publish (plain->L2 + agent->MALL) with 1:1 alternating poll is the
//    validated sync (R7 13.3 vs agent-only R12 16.1 vs fast-heavy R10 29.6)
//  - wave-0 combine with stride-64 part reads is conflict-free; distributed
//    shuffle-combine (R13) adds 5e7 bank conflicts and loses 8ms
//  - NEW (R14): compiler NEVER kept r[64] in VGPRs (VGPR_Count 52-64 across
//    R6-R13; "+v" pins defeated twice) -> each lane re-streamed 256B of
//    weights per step (~256KB/WG/step through L1/L2), the dominant stall.
//    Fix: hold weights in AGPRs via v_accvgpr_write/read ("a" constraint,
//    unified VGPR/AGPR file on gfx950) -- cannot be sunk to memory.
#define K_WG        16
#define COLS_PER_WG 64
#define GRID        128
#define WGSIZE      1024

#define ENTRIES     (NMOD * UNITS)   // 4096 packed entries per buffer
// d_ws layout: slow[2][ENTRIES] then fast[2][ENTRIES], 64-bit {tag|value}.
#define WS_ULL      (4 * ENTRIES)

__global__ void init_ws_kernel(unsigned long long* __restrict__ b) {
    int i = blockIdx.x * blockDim.x + threadIdx.x;
    if (i < WS_ULL) b[i] = 0ULL;     // tag 0 < any t in 1..T
}

// tanh via exp2 + rcp: ~1e-6 rel err, correct saturation (verified R4).
__device__ __forceinline__ float tanh_fast(float x) {
    float e2x = __builtin_amdgcn_exp2f(x * 2.8853900817779268f); // 2*log2(e)
    float r   = __builtin_amdgcn_rcpf(e2x + 1.0f);
    return fmaf(-2.0f, r, 1.0f);
}

// L1-bypass (sc0) 8-byte load: served coherently from the LOCAL XCD's L2.
__device__ __forceinline__ unsigned long long load_l2(
        const unsigned long long* p) {
    unsigned long long v;
    asm volatile("global_load_dwordx2 %0, %1, off sc0\n\t"
                 "s_waitcnt vmcnt(0)"
                 : "=v"(v) : "v"(p) : "memory");
    return v;
}

__global__ __launch_bounds__(WGSIZE, 1)
void reservoir_persist(const float* __restrict__ u,
                       const float* __restrict__ kern,
                       const float* __restrict__ rec,
                       const float* __restrict__ bias,
                       float* __restrict__ out,
                       unsigned long long* __restrict__ slow,
                       unsigned long long* __restrict__ fast)
{
    const int wg  = blockIdx.x;
    const int res = wg & 7;
    if (res >= NMOD) return;             // residues 4..7 idle
    const int m   = res;                 // module 0..3
    const int wgi = wg >> 3;             // 0..15 within module

    const int tid  = threadIdx.x;
    const int w    = tid >> 6;           // wave 0..15  (row-slice owner)
    const int lane = tid & 63;

    const int c       = wgi * COLS_PER_WG + lane;  // my column (module-local)
    const int rowBase = 64 * w;                    // my wave's h-row slice

    __shared__ __align__(16) float h_slice[16][64]; // wave-private row slices
    __shared__ float part[2][16][64];               // double-buffered partials

    // ---- one-time preload of weights -> AGPRs (true residency) ----
    const float* recm = rec + (size_t)m * UNITS * UNITS;
    float ra[64];                        // allocated in AGPRs via "a" asm
#pragma unroll
    for (int j = 0; j < 16; ++j)
#pragma unroll
        for (int e = 0; e < 4; ++e) {
            float t = recm[(size_t)(rowBase + 4 * j + e) * UNITS + c];
            asm volatile("v_accvgpr_write_b32 %0, %1"
                         : "=a"(ra[4 * j + e]) : "v"(t));
        }

    // input kernel slice: wave w folds u-rows [4w, 4w+4)
    const float* km = kern + (size_t)m * INPUT * UNITS;
    const float k0 = km[(size_t)(4 * w + 0) * UNITS + c];
    const float k1 = km[(size_t)(4 * w + 1) * UNITS + c];
    const float k2 = km[(size_t)(4 * w + 2) * UNITS + c];
    const float k3 = km[(size_t)(4 * w + 3) * UNITS + c];
    const float bc = bias[m * UNITS + c];

    const float leak = LEAKY, omleak = 1.0f - LEAKY;

    h_slice[w][lane] = 0.0f;             // h_0 = 0 (wave-private slice)
    float hprev = 0.0f;                  // wave 0: my column's h state
    __syncthreads();

    const size_t modOff = (size_t)m * UNITS;

    // u quad for step 1 (uses u[0]); uniform per wave
    float4 uq = *reinterpret_cast<const float4*>(u + 4 * w);

    for (int t = 1; t <= T_STEPS; ++t) {
        const int pb = t & 1;

        // ---- FMA phase: rows [64w,64w+64) x my column ----
        // h via uniform-address LDS broadcast; weights read back from AGPRs
        // (v_accvgpr_read, 1 VALU op each -- no memory traffic).
        const float4* __restrict__ hs4 =
            reinterpret_cast<const float4*>(h_slice[w]);
        float a0 = uq.x * k0, a1 = uq.y * k1, a2 = uq.z * k2, a3 = uq.w * k3;
#pragma unroll
        for (int j = 0; j < 16; ++j) {
            float4 hv4 = hs4[j];         // uniform address -> HW broadcast
            float w0, w1, w2, w3;
            asm("v_accvgpr_read_b32 %0, %1" : "=v"(w0) : "a"(ra[4 * j + 0]));
            asm("v_accvgpr_read_b32 %0, %1" : "=v"(w1) : "a"(ra[4 * j + 1]));
            asm("v_accvgpr_read_b32 %0, %1" : "=v"(w2) : "a"(ra[4 * j + 2]));
            asm("v_accvgpr_read_b32 %0, %1" : "=v"(w3) : "a"(ra[4 * j + 3]));
            a0 = fmaf(w0, hv4.x, a0);
            a1 = fmaf(w1, hv4.y, a1);
            a2 = fmaf(w2, hv4.z, a2);
            a3 = fmaf(w3, hv4.w, a3);
        }
        part[pb][w][lane] = (a0 + a1) + (a2 + a3);
        __syncthreads();   // partials of step t visible; only barrier/step

        unsigned long long* fbW = fast + (size_t)pb * ENTRIES + modOff;
        unsigned long long* sbW = slow + (size_t)pb * ENTRIES + modOff;

        // ---- combine + publish (wave 0; lane l -> column c) ----
        // part[pb] reuse (next write at t+2) is race-free: wave w's
        // part[pb] write at t+2 requires its (t+1)-poll, which requires
        // every WG's (t+1)-publish, which is program-ordered (in that WG's
        // wave 0) after its t-combine reads here. Stride-64 reads: lanes
        // l and l+32 alias each bank (2-way = free, R4-R8: 0 conflicts).
        if (w == 0) {
            float s0 = part[pb][0][lane] + part[pb][1][lane];
            float s1 = part[pb][2][lane] + part[pb][3][lane];
            float s2 = part[pb][4][lane] + part[pb][5][lane];
            float s3 = part[pb][6][lane] + part[pb][7][lane];
#pragma unroll
            for (int ww = 8; ww < 16; ww += 4) {
                s0 += part[pb][ww][lane];     s1 += part[pb][ww + 1][lane];
                s2 += part[pb][ww + 2][lane]; s3 += part[pb][ww + 3][lane];
            }
            float s = (s0 + s1) + (s2 + s3);
            float hn = omleak * hprev + leak * tanh_fast(s + bc);
            hprev = hn;
            unsigned long long pk =
                ((unsigned long long)(unsigned int)t << 32) |
                (unsigned long long)__float_as_uint(hn);
            // fast: plain store -> local XCD L2 (sc0-visible there)
            __hip_atomic_store(&fbW[c], pk, __ATOMIC_RELAXED,
                               __HIP_MEMORY_SCOPE_WORKGROUP);
            // slow: agent store -> MALL (any placement)
            __hip_atomic_store(&sbW[c], pk, __ATOMIC_RELAXED,
                               __HIP_MEMORY_SCOPE_AGENT);
        }

        // prefetch next u quad (latency overlaps the poll)
        if (t < T_STEPS)
            uq = *reinterpret_cast<const float4*>(u + (size_t)t * INPUT + 4 * w);

        // ---- poll my row slice (entry tid = 64w+lane): 1:1 fast/slow ----
        unsigned long long v;
        for (;;) {
            v = load_l2(&fbW[tid]);
            if ((unsigned int)(v >> 32) == (unsigned int)t) break;
            v = __hip_atomic_load(&sbW[tid], __ATOMIC_RELAXED,
                                  __HIP_MEMORY_SCOPE_AGENT);
            if ((unsigned int)(v >> 32) == (unsigned int)t) break;
        }
        const float hv = __uint_as_float((unsigned int)v);
        h_slice[w][lane] = hv;           // wave-private; in-wave ds ordering

        // one WG per module writes the coalesced output row (off crit path)
        if (wgi == 0)
            out[(size_t)(t - 1) * (NMOD * UNITS) + modOff + tid] = hv;
    }
}

extern "C" void kernel_launch(void* const* d_in, const int* in_sizes, int n_in,
                              void* d_out, int out_size, void* d_ws, size_t ws_size,
                              hipStream_t stream) {
    const float* u    = (const float*)d_in[0];  // [1, 8192, 64]
    const float* kern = (const float*)d_in[1];  // [4, 64, 1024]
    const float* rec  = (const float*)d_in[2];  // [4, 1024, 1024]
    const float* bias = (const float*)d_in[3];  // [4, 1024]
    float* out = (float*)d_out;                 // [1, 8192, 4096] f32

    unsigned long long* slow = (unsigned long long*)d_ws;              // 64 KB
    unsigned long long* fast = slow + 2 * ENTRIES;                     // 64 KB

    hipLaunchKernelGGL(init_ws_kernel, dim3((WS_ULL + 1023) / 1024), dim3(1024),
                       0, stream, slow);

    void* args[] = { (void*)&u, (void*)&kern, (void*)&rec, (void*)&bias,
                     (void*)&out, (void*)&slow, (void*)&fast };
    hipLaunchCooperativeKernel((const void*)reservoir_persist,
                               dim3(GRID), dim3(WGSIZE), args, 0, stream);
}

// Round 16
// 16327.122 us; speedup vs baseline: 1.3046x; 1.1639x over previous
//
#include <hip/hip_runtime.h>
#include <math.h>

// Problem constants (from reference)
#define T_STEPS 8192
#define INPUT   64
#define UNITS   1024
#define NMOD    4
#define LEAKY   0.9f

// Decomposition (R7 structure, best-known 13.3ms): 16 WGs per module;
// module = blockIdx%8 residues 0..3 (4..7 exit). WG = 1024 threads = 16
// waves. Lane l of EVERY wave owns column c = wgi*64+l for the POLL; wave w
// handles h-rows [64w,64w+64): consumes exactly WG w's publish, deposits it
// in a wave-private LDS slice, re-reads as 16 uniform-address float4
// broadcasts, FMAs against 64 per-lane weights. Partials combine in LDS
// after ONE barrier; wave 0 finishes (bias+tanh+blend) and dual-publishes.
//
// Hard-won rules:
//  - per-step __syncthreads is LOAD-BEARING (R5/R9: removal -> 2-7x collapse)
//  - dual publish (plain->L2 + agent->MALL) with alternating poll is the
//    validated liveness-safe sync (R7 13.3 / R12 agent-only 16.1)
//  - per-lane fast-spin saturates the XCD L2 (R10: 29.6ms); placement
//    election deadlocks (R15 timeout) -- never "some exit, others wait"
//  - wave-0 combine beats shuffle-combine (R13: +5e7 bank conflicts)
//  - weights are L2-resident; AGPR pinning hurts (R14: 19.0ms)
//
// NEW (R16): SENTINEL polling. Wave w's 64 entries come from ONE producer
// store burst, so detection needs one word: all 64 lanes poll fbW[64w]
// (uniform address = 1 coalesced L2 request/wave/iter, 4-8x less traffic
// than R7's per-lane loop, 64x fewer distinct addresses than R10).
// Alternating fast/slow sentinel preserves R7's worst-case period and
// liveness for arbitrary placement; fast hits break at ~250cy. Per-lane
// entry loads run only after detection (~once, R7 fallback for stragglers).
#define K_WG        16
#define COLS_PER_WG 64
#define GRID        128
#define WGSIZE      1024

#define ENTRIES     (NMOD * UNITS)   // 4096 packed entries per buffer
// d_ws layout: slow[2][ENTRIES] then fast[2][ENTRIES], 64-bit {tag|value}.
#define WS_ULL      (4 * ENTRIES)

__global__ void init_ws_kernel(unsigned long long* __restrict__ b) {
    int i = blockIdx.x * blockDim.x + threadIdx.x;
    if (i < WS_ULL) b[i] = 0ULL;     // tag 0 < any t in 1..T
}

// tanh via exp2 + rcp: ~1e-6 rel err, correct saturation (verified R4).
__device__ __forceinline__ float tanh_fast(float x) {
    float e2x = __builtin_amdgcn_exp2f(x * 2.8853900817779268f); // 2*log2(e)
    float r   = __builtin_amdgcn_rcpf(e2x + 1.0f);
    return fmaf(-2.0f, r, 1.0f);
}

// L1-bypass (sc0) 8-byte load: served coherently from the LOCAL XCD's L2.
__device__ __forceinline__ unsigned long long load_l2(
        const unsigned long long* p) {
    unsigned long long v;
    asm volatile("global_load_dwordx2 %0, %1, off sc0\n\t"
                 "s_waitcnt vmcnt(0)"
                 : "=v"(v) : "v"(p) : "memory");
    return v;
}

__global__ __launch_bounds__(WGSIZE, 1)
void reservoir_persist(const float* __restrict__ u,
                       const float* __restrict__ kern,
                       const float* __restrict__ rec,
                       const float* __restrict__ bias,
                       float* __restrict__ out,
                       unsigned long long* __restrict__ slow,
                       unsigned long long* __restrict__ fast)
{
    const int wg  = blockIdx.x;
    const int res = wg & 7;
    if (res >= NMOD) return;             // residues 4..7 idle
    const int m   = res;                 // module 0..3
    const int wgi = wg >> 3;             // 0..15 within module

    const int tid  = threadIdx.x;
    const int w    = tid >> 6;           // wave 0..15  (row-slice owner)
    const int lane = tid & 63;

    const int c       = wgi * COLS_PER_WG + lane;  // my column (module-local)
    const int rowBase = 64 * w;                    // my wave's h-row slice

    __shared__ __align__(16) float h_slice[16][64]; // wave-private row slices
    __shared__ float part[2][16][64];               // double-buffered partials

    // ---- one-time preload of weights ----
    const float* recm = rec + (size_t)m * UNITS * UNITS;
    float r[64];
#pragma unroll
    for (int j = 0; j < 16; ++j)
#pragma unroll
        for (int e = 0; e < 4; ++e)
            r[4 * j + e] = recm[(size_t)(rowBase + 4 * j + e) * UNITS + c];
#pragma unroll
    for (int j = 0; j < 64; ++j) asm volatile("" : "+v"(r[j]));

    // input kernel slice: wave w folds u-rows [4w, 4w+4)
    const float* km = kern + (size_t)m * INPUT * UNITS;
    const float k0 = km[(size_t)(4 * w + 0) * UNITS + c];
    const float k1 = km[(size_t)(4 * w + 1) * UNITS + c];
    const float k2 = km[(size_t)(4 * w + 2) * UNITS + c];
    const float k3 = km[(size_t)(4 * w + 3) * UNITS + c];
    const float bc = bias[m * UNITS + c];

    const float leak = LEAKY, omleak = 1.0f - LEAKY;

    h_slice[w][lane] = 0.0f;             // h_0 = 0 (wave-private slice)
    float hprev = 0.0f;                  // wave 0: my column's h state
    __syncthreads();

    const size_t modOff = (size_t)m * UNITS;

    // u quad for step 1 (uses u[0]); uniform per wave
    float4 uq = *reinterpret_cast<const float4*>(u + 4 * w);

    for (int t = 1; t <= T_STEPS; ++t) {
        const int pb = t & 1;

        // ---- FMA phase: rows [64w,64w+64) x my column, h via LDS broadcast
        const float4* __restrict__ hs4 =
            reinterpret_cast<const float4*>(h_slice[w]);
        float a0 = uq.x * k0, a1 = uq.y * k1, a2 = uq.z * k2, a3 = uq.w * k3;
#pragma unroll
        for (int j = 0; j < 16; ++j) {
            float4 hv4 = hs4[j];         // uniform address -> HW broadcast
            a0 = fmaf(r[4 * j + 0], hv4.x, a0);
            a1 = fmaf(r[4 * j + 1], hv4.y, a1);
            a2 = fmaf(r[4 * j + 2], hv4.z, a2);
            a3 = fmaf(r[4 * j + 3], hv4.w, a3);
        }
        part[pb][w][lane] = (a0 + a1) + (a2 + a3);
        __syncthreads();   // partials of step t visible; only barrier/step

        unsigned long long* fbW = fast + (size_t)pb * ENTRIES + modOff;
        unsigned long long* sbW = slow + (size_t)pb * ENTRIES + modOff;

        // ---- combine + publish (wave 0; lane l -> column c) ----
        // part[pb] reuse (next write at t+2) is race-free: wave w's
        // part[pb] write at t+2 requires its (t+1)-poll, which requires
        // every WG's (t+1)-publish, which is program-ordered (in that WG's
        // wave 0) after its t-combine reads here. Stride-64 reads: 2-way
        // bank aliasing = free (R4-R12: SQ_LDS_BANK_CONFLICT == 0).
        if (w == 0) {
            float s0 = part[pb][0][lane] + part[pb][1][lane];
            float s1 = part[pb][2][lane] + part[pb][3][lane];
            float s2 = part[pb][4][lane] + part[pb][5][lane];
            float s3 = part[pb][6][lane] + part[pb][7][lane];
#pragma unroll
            for (int ww = 8; ww < 16; ww += 4) {
                s0 += part[pb][ww][lane];     s1 += part[pb][ww + 1][lane];
                s2 += part[pb][ww + 2][lane]; s3 += part[pb][ww + 3][lane];
            }
            float s = (s0 + s1) + (s2 + s3);
            float hn = omleak * hprev + leak * tanh_fast(s + bc);
            hprev = hn;
            unsigned long long pk =
                ((unsigned long long)(unsigned int)t << 32) |
                (unsigned long long)__float_as_uint(hn);
            // fast: plain store -> local XCD L2 (sc0-visible there)
            __hip_atomic_store(&fbW[c], pk, __ATOMIC_RELAXED,
                               __HIP_MEMORY_SCOPE_WORKGROUP);
            // slow: agent store -> MALL (correct for any placement)
            __hip_atomic_store(&sbW[c], pk, __ATOMIC_RELAXED,
                               __HIP_MEMORY_SCOPE_AGENT);
        }

        // prefetch next u quad (latency overlaps the poll)
        if (t < T_STEPS)
            uq = *reinterpret_cast<const float4*>(u + (size_t)t * INPUT + 4 * w);

        // ---- SENTINEL wait: all lanes poll ONE word (uniform address) ----
        // Wave w's 64 entries are published by WG w's wave-0 single store
        // burst, so one sentinel word detects the whole slice. 1 coalesced
        // L2 request/wave/iter. Alternating fast/slow = R7 liveness.
        const unsigned long long* sentF = &fbW[64 * w];
        const unsigned long long* sentS = &sbW[64 * w];
        for (;;) {
            unsigned long long sv = load_l2(sentF);
            if ((unsigned int)(sv >> 32) == (unsigned int)t) break;
            sv = __hip_atomic_load(sentS, __ATOMIC_RELAXED,
                                   __HIP_MEMORY_SCOPE_AGENT);
            if ((unsigned int)(sv >> 32) == (unsigned int)t) break;
        }

        // ---- per-lane entry load (runs ~once; R7 fallback for stragglers)
        unsigned long long v;
        for (;;) {
            v = load_l2(&fbW[tid]);
            if ((unsigned int)(v >> 32) == (unsigned int)t) break;
            v = __hip_atomic_load(&sbW[tid], __ATOMIC_RELAXED,
                                  __HIP_MEMORY_SCOPE_AGENT);
            if ((unsigned int)(v >> 32) == (unsigned int)t) break;
        }
        const float hv = __uint_as_float((unsigned int)v);
        h_slice[w][lane] = hv;           // wave-private; in-wave ds ordering

        // one WG per module writes the coalesced output row (off crit path)
        if (wgi == 0)
            out[(size_t)(t - 1) * (NMOD * UNITS) + modOff + tid] = hv;
    }
}

extern "C" void kernel_launch(void* const* d_in, const int* in_sizes, int n_in,
                              void* d_out, int out_size, void* d_ws, size_t ws_size,
                              hipStream_t stream) {
    const float* u    = (const float*)d_in[0];  // [1, 8192, 64]
    const float* kern = (const float*)d_in[1];  // [4, 64, 1024]
    const float* rec  = (const float*)d_in[2];  // [4, 1024, 1024]
    const float* bias = (const float*)d_in[3];  // [4, 1024]
    float* out = (float*)d_out;                 // [1, 8192, 4096] f32

    unsigned long long* slow = (unsigned long long*)d_ws;              // 64 KB
    unsigned long long* fast = slow + 2 * ENTRIES;                     // 64 KB

    hipLaunchKernelGGL(init_ws_kernel, dim3((WS_ULL + 1023) / 1024), dim3(1024),
                       0, stream, slow);

    void* args[] = { (void*)&u, (void*)&kern, (void*)&rec, (void*)&bias,
                     (void*)&out, (void*)&slow, (void*)&fast };
    hipLaunchCooperativeKernel((const void*)reservoir_persist,
                               dim3(GRID), dim3(WGSIZE), args, 0, stream);
}